// Round 7
// baseline (226.884 us; speedup 1.0000x reference)
//
#include <hip/hip_runtime.h>
#include <math.h>

#define W48 48
#define HD 2304
#define WHD 110592
#define NR 32
#define NB 8
#define GPP 55296            // float2 groups per (b,r) plane
#define TPB 256
#define CHUNKS 216           // GPP / 256
#define MAIN_BLOCKS 1728     // NB * CHUNKS
#define NTOT 28311552.0

struct PPart { float s0, sx, sy, mv; unsigned idx; }; // 20 B

// ws layout (bytes)
#define PP_OFF   0u
#define BLK_OFF  1105920u              // 1728*32*20
#define PD_OFF   1175040u              // + 1728*5*8
#define DP_OFF   1177088u              // + 256*8
#define CNT_OFF  1187328u              // + 256*5*8

// ---- fused single-pass kernel: float2/thread, 8-r LDS quarters, block-major pp ----
__global__ __launch_bounds__(256, 8)   // cap VGPR at 64 -> 8 waves/SIMD possible
void k_main(const float* __restrict__ feat, PPart* __restrict__ pp,
            double* __restrict__ blk) {
  __shared__ float lds_s0[8 * 256];    // 8 KB [r8][t]
  __shared__ float lds_mv[8 * 256];    // 8 KB [r8][t]
  __shared__ unsigned lds_mc[256];     // 1 KB packed z-bit, 1b per r8
  __shared__ float comb_s0[4][8], comb_sx[4][8], comb_sy[4][8], comb_mv[4][8];
  __shared__ unsigned comb_idx[4][8];
  __shared__ double ld[4][5];

  const int bid = blockIdx.x;
  const int t = threadIdx.x;
  const int b = bid / CHUNKS;
  const int chunk = bid - b * CHUNKS;
  const int g = chunk * 256 + t;                  // float2 group within plane
  const float2* gptr = reinterpret_cast<const float2*>(feat) + (size_t)b * (NR * GPP) + g;

  const int p0 = g * 2;
  const float fi = (float)(p0 / HD);
  const float fj = (float)((p0 / W48) % W48);     // constant over the 2 elems (2 | 48)
  const float rrq = fi * fi + fj * fj;

  float v1[2], v2[2], cp[2];
#pragma unroll
  for (int c = 0; c < 2; ++c) { v1[c] = -INFINITY; v2[c] = -INFINITY; cp[c] = 0.f; }
  float ssum = 0.f, sii = 0.f;
  unsigned mcpack = 0u;

  float2 nb0 = gptr[0];
  float2 nb1 = gptr[(size_t)GPP];
  float2 nb2 = gptr[2 * (size_t)GPP];
  float2 nb3 = gptr[3 * (size_t)GPP];

  const int wave = t >> 6, lane = t & 63;

  for (int quarter = 0; quarter < 4; ++quarter) {
#pragma unroll
    for (int rr = 0; rr < 8; ++rr) {
      const int r = quarter * 8 + rr;
      float2 v = nb0; nb0 = nb1; nb1 = nb2; nb2 = nb3;
      int rn = r + 4; rn = (rn < NR) ? rn : (NR - 1);   // clamped redundant tail load
      nb3 = gptr[(size_t)rn * GPP];

      float x = v.x, y = v.y;
      float f2x = x * x, f2y = y * y;
      cp[0] += f2x; cp[1] += f2y;
      float nv2 = fmaxf(x, v2[0]);
      v2[0] = (x > v1[0]) ? v1[0] : nv2; v1[0] = fmaxf(v1[0], x);   // top-2, first-index
      nv2 = fmaxf(y, v2[1]);
      v2[1] = (y > v1[1]) ? v1[1] : nv2; v1[1] = fmaxf(v1[1], y);
      ssum += x + y;
      float s0t = f2x + f2y;
      sii += s0t * rrq;

      float mv = fmaxf(x, y);
      mcpack |= ((y > x) ? 1u : 0u) << rr;     // strict >: x (lower idx) wins ties
      lds_s0[rr * 256 + t] = s0t;
      lds_mv[rr * 256 + t] = mv;
    }

    // ---- epilogue: transpose-reduce 8 r's in parallel (8 er x 32 eg) ----
    lds_mc[t] = mcpack; mcpack = 0u;
    __syncthreads();                           // arena writes visible
    const int er = t & 7;                      // which r this thread reduces
    const int eg = t >> 3;                     // which 8-row group
    float es0 = 0.f, esx = 0.f, esy = 0.f;
    float bmv = -INFINITY; int brow = 0;
#pragma unroll
    for (int k = 0; k < 8; ++k) {
      int row = eg * 8 + ((k + er) & 7);       // rotation: 2-way bank alias only (free)
      float s0v = lds_s0[er * 256 + row];
      float mvv = lds_mv[er * 256 + row];
      unsigned q = (unsigned)(chunk * 256 + row);
      float fiq = (float)(q / 1152u);          // i = (q*2)/2304
      float fjq = (float)((q / 24u) % 48u);    // j = (q*2/48)%48
      es0 += s0v;
      esx = fmaf(s0v, fiq, esx);
      esy = fmaf(s0v, fjq, esy);
      if (mvv > bmv || (mvv == bmv && row < brow)) { bmv = mvv; brow = row; }
    }
    unsigned bidx = (unsigned)((chunk * 256 + brow) * 2) + ((lds_mc[brow] >> er) & 1u);

    // combine the 8 eg-partials per er within the wave (lane bits 3,4,5)
#pragma unroll
    for (int m = 8; m <= 32; m <<= 1) {
      es0 += __shfl_xor(es0, m);
      esx += __shfl_xor(esx, m);
      esy += __shfl_xor(esy, m);
      float omv = __shfl_xor(bmv, m);
      unsigned oix = (unsigned)__shfl_xor((int)bidx, m);
      if (omv > bmv || (omv == bmv && oix < bidx)) { bmv = omv; bidx = oix; }
    }
    if (lane < 8) {
      comb_s0[wave][lane] = es0; comb_sx[wave][lane] = esx; comb_sy[wave][lane] = esy;
      comb_mv[wave][lane] = bmv; comb_idx[wave][lane] = bidx;
    }
    __syncthreads();                           // comb visible + arena reads done
    if (t < 8) {
      float ps0 = 0.f, psx = 0.f, psy = 0.f, pmv = -INFINITY;
      unsigned pidx = 0xffffffffu;
#pragma unroll
      for (int w = 0; w < 4; ++w) {
        ps0 += comb_s0[w][t]; psx += comb_sx[w][t]; psy += comb_sy[w][t];
        if (comb_mv[w][t] > pmv || (comb_mv[w][t] == pmv && comb_idx[w][t] < pidx)) {
          pmv = comb_mv[w][t]; pidx = comb_idx[w][t];
        }
      }
      // BLOCK-MAJOR, 64B-aligned per block (32*20=640B): no cross-XCD false sharing
      PPart o; o.s0 = ps0; o.sx = psx; o.sy = psy; o.mv = pmv; o.idx = pidx;
      pp[(size_t)bid * 32 + quarter * 8 + t] = o;
    }
    __syncthreads();                           // arena reuse for next quarter
  }

  // ---- div epilogue (f2@argmax == v1^2) + global sums ----
  float A = 0.f, Bs = 0.f, C = 0.f;
#pragma unroll
  for (int c = 0; c < 2; ++c) {
    float m1 = v1[c], m1sq = m1 * m1;
    float rest = cp[c] - m1sq;
    A  += m1sq * rest + v2[c] * v2[c] * m1sq;
    Bs += m1 * rest + v2[c] * m1sq;
    C  += cp[c];
  }
  double dA = A, dB = Bs, dC = C, dS = ssum, dI = sii;
#pragma unroll
  for (int off = 32; off; off >>= 1) {
    dA += __shfl_down(dA, off);
    dB += __shfl_down(dB, off);
    dC += __shfl_down(dC, off);
    dS += __shfl_down(dS, off);
    dI += __shfl_down(dI, off);
  }
  if (lane == 0) { ld[wave][0]=dA; ld[wave][1]=dB; ld[wave][2]=dC; ld[wave][3]=dS; ld[wave][4]=dI; }
  __syncthreads();
  if (t == 0) {
    double a=0, bb=0, cc=0, ss=0, si=0;
#pragma unroll
    for (int w = 0; w < 4; ++w) { a+=ld[w][0]; bb+=ld[w][1]; cc+=ld[w][2]; ss+=ld[w][3]; si+=ld[w][4]; }
    blk[(size_t)bid*5+0]=a; blk[(size_t)bid*5+1]=bb; blk[(size_t)bid*5+2]=cc;
    blk[(size_t)bid*5+3]=ss; blk[(size_t)bid*5+4]=si;
  }
}

// ------------- fused finalize: per-plane combine + last-block final scalars -------------
__global__ __launch_bounds__(256)
void k_reduce(const PPart* __restrict__ pp, const double* __restrict__ blk,
              double* __restrict__ planeDis, double* __restrict__ divpart,
              unsigned* __restrict__ counter, float* __restrict__ out) {
  __shared__ double ls[4][3];
  __shared__ float lmv4[4];
  __shared__ unsigned lidx4[4];
  __shared__ double fin[4][6];
  __shared__ int lastFlag;

  const int p = blockIdx.x;               // plane = b*32 + r
  const int t = threadIdx.x;
  const int wave = t >> 6, lane = t & 63;
  const int b = p >> 5, r = p & 31;

  // ---- part 1: combine 216 chunk-partials of plane p ----
  double s0 = 0, sx = 0, sy = 0;
  float mv = -INFINITY; unsigned idx = 0xffffffffu;
  if (t < CHUNKS) {
    PPart v = pp[((size_t)(b * CHUNKS + t)) * 32 + r];
    s0 = v.s0; sx = v.sx; sy = v.sy; mv = v.mv; idx = v.idx;
  }
#pragma unroll
  for (int off = 32; off; off >>= 1) {
    s0 += __shfl_down(s0, off);
    sx += __shfl_down(sx, off);
    sy += __shfl_down(sy, off);
    float omv = __shfl_down(mv, off);
    unsigned oix = (unsigned)__shfl_down((int)idx, off);
    if (omv > mv || (omv == mv && oix < idx)) { mv = omv; idx = oix; }
  }
  if (lane == 0) { ls[wave][0] = s0; ls[wave][1] = sx; ls[wave][2] = sy; lmv4[wave] = mv; lidx4[wave] = idx; }
  __syncthreads();
  if (t == 0) {
    double a0 = 0, a1 = 0, a2 = 0; float bm = -INFINITY; unsigned bi = 0xffffffffu;
#pragma unroll
    for (int w = 0; w < 4; ++w) {
      a0 += ls[w][0]; a1 += ls[w][1]; a2 += ls[w][2];
      if (lmv4[w] > bm || (lmv4[w] == bm && lidx4[w] < bi)) { bm = lmv4[w]; bi = lidx4[w]; }
    }
    int am = (int)bi;
    int mx = am / HD;
    int rem = am - mx * HD;
    int my = rem / W48;
    int mz = rem - my * W48;
    double dmx = mx, dmy = my, dmz = mz;
    // sum_k (mz-k)^2, k=0..47 = 48 mz^2 - 2256 mz + 35720 ; times W*H=2304
    planeDis[p] = (dmx*dmx + dmy*dmy) * a0 - 2.0*dmx*a1 - 2.0*dmy*a2
                + 2304.0 * (48.0*dmz*dmz - 2256.0*dmz + 35720.0);
  }

  // ---- part 2: this block's slice of div/global sums (rows p, p+256, ...) ----
  double A = 0, Bs = 0, C = 0, S = 0, SI = 0;
  if (t < 7) {
    int i = p + 256 * t;
    if (i < MAIN_BLOCKS) {
      const double* bb = blk + (size_t)i * 5;
      A = bb[0]; Bs = bb[1]; C = bb[2]; S = bb[3]; SI = bb[4];
    }
  }
#pragma unroll
  for (int off = 4; off; off >>= 1) {
    A  += __shfl_down(A, off);
    Bs += __shfl_down(Bs, off);
    C  += __shfl_down(C, off);
    S  += __shfl_down(S, off);
    SI += __shfl_down(SI, off);
  }
  if (t == 0) {
    double* dp = divpart + (size_t)p * 5;
    dp[0] = A; dp[1] = Bs; dp[2] = C; dp[3] = S; dp[4] = SI;
  }
  __syncthreads();

  // ---- last-block final reduction ----
  if (t == 0) {
    __threadfence();                              // release planeDis/divpart
    unsigned old = atomicAdd(counter, 1u);        // device-scope
    lastFlag = (old == 255u);
  }
  __syncthreads();
  if (lastFlag) {
    __threadfence();                              // acquire other blocks' writes
    double dis = planeDis[t];                     // 256 threads = 256 planes
    const double* dp = divpart + (size_t)t * 5;
    double fA = dp[0], fB = dp[1], fC = dp[2], fS = dp[3], fI = dp[4];
#pragma unroll
    for (int off = 32; off; off >>= 1) {
      dis += __shfl_down(dis, off);
      fA  += __shfl_down(fA, off);
      fB  += __shfl_down(fB, off);
      fC  += __shfl_down(fC, off);
      fS  += __shfl_down(fS, off);
      fI  += __shfl_down(fI, off);
    }
    if (lane == 0) {
      fin[wave][0] = dis; fin[wave][1] = fA; fin[wave][2] = fB;
      fin[wave][3] = fC;  fin[wave][4] = fS; fin[wave][5] = fI;
    }
    __syncthreads();
    if (t == 0) {
      double td = 0, tA = 0, tB = 0, tC = 0, tS = 0, tI = 0;
#pragma unroll
      for (int w = 0; w < 4; ++w) {
        td += fin[w][0]; tA += fin[w][1]; tB += fin[w][2];
        tC += fin[w][3]; tS += fin[w][4]; tI += fin[w][5];
      }
      double mgr = tS / NTOT;
      out[0] = (float)((td + tI) / NTOT);
      out[1] = (float)((tA - 2.0*mgr*tB + mgr*mgr*tC) / NTOT);
    }
  }
}

extern "C" void kernel_launch(void* const* d_in, const int* in_sizes, int n_in,
                              void* d_out, int out_size, void* d_ws, size_t ws_size,
                              hipStream_t stream) {
  // inputs: [0]=backbone_feature (unused), [1]=grouping_result (unused), [2]=feature
  const float* feat = (const float*)d_in[2];
  float* out = (float*)d_out;

  PPart* pp        = (PPart*)((char*)d_ws + PP_OFF);
  double* blk      = (double*)((char*)d_ws + BLK_OFF);
  double* planeDis = (double*)((char*)d_ws + PD_OFF);
  double* divpart  = (double*)((char*)d_ws + DP_OFF);
  unsigned* cnt    = (unsigned*)((char*)d_ws + CNT_OFF);

  hipMemsetAsync(cnt, 0, 4, stream);              // reset last-block counter each launch
  k_main<<<MAIN_BLOCKS, TPB, 0, stream>>>(feat, pp, blk);
  k_reduce<<<256, 256, 0, stream>>>(pp, blk, planeDis, divpart, cnt, out);
}

// Round 8
// 62.662 us; speedup vs baseline: 3.6207x; 3.6207x over previous
//
#include <hip/hip_runtime.h>
#include <math.h>

#define W48 48
#define HD 2304
#define WHD 110592
#define NR 32
#define NB 8
#define GPP 55296            // float2 groups per (b,r) plane
#define TPB 256
#define CHUNKS 216           // GPP / 256
#define MAIN_BLOCKS 1728     // NB * CHUNKS
#define NPLANES 256
#define NTOT 28311552.0

struct PPartP { float s0, sx, sy, mv; unsigned idx; unsigned pad[3]; }; // 32 B padded

// ws layout (bytes)
#define PP_OFF   0u
#define BLK_OFF  1769472u              // 216*256*32
#define PD_OFF   1880064u              // + 1728*8*8
#define DP_OFF   1882112u              // + 256*8
#define CNT_OFF  1892352u              // + 256*5*8

// ---- fused single-pass kernel: float2/thread, 8-r LDS quarters ----
__global__ __launch_bounds__(256, 6)   // 85-VGPR cap; natural footprint ~40 -> no spill
void k_main(const float* __restrict__ feat, PPartP* __restrict__ pp,
            double* __restrict__ blk) {
  __shared__ float lds_s0[8 * 256];    // 8 KB [r8][t]
  __shared__ float lds_mv[8 * 256];    // 8 KB [r8][t]
  __shared__ unsigned lds_mc[256];     // 1 KB packed z-bit, 1b per r8
  __shared__ float comb_s0[4][8], comb_sx[4][8], comb_sy[4][8], comb_mv[4][8];
  __shared__ unsigned comb_idx[4][8];
  __shared__ double ld[4][5];

  const int bid = blockIdx.x;
  const int t = threadIdx.x;
  const int b = bid / CHUNKS;
  const int chunk = bid - b * CHUNKS;
  const int g = chunk * 256 + t;                  // float2 group within plane
  const float2* gptr = reinterpret_cast<const float2*>(feat) + (size_t)b * (NR * GPP) + g;

  const int p0 = g * 2;
  const float fi = (float)(p0 / HD);
  const float fj = (float)((p0 / W48) % W48);     // constant over the 2 elems (2 | 48)
  const float rrq = fi * fi + fj * fj;

  float v1x = -INFINITY, v1y = -INFINITY, v2x = -INFINITY, v2y = -INFINITY;
  float cpx = 0.f, cpy = 0.f, ssum = 0.f, sii = 0.f;
  unsigned mcpack = 0u;
  const int wave = t >> 6, lane = t & 63;

  float2 nb0 = gptr[0];
  float2 nb1 = gptr[(size_t)GPP];
  float2 nb2 = gptr[2 * (size_t)GPP];
  float2 nb3 = gptr[3 * (size_t)GPP];

  for (int quarter = 0; quarter < 4; ++quarter) {
#pragma unroll 4
    for (int rr = 0; rr < 8; ++rr) {
      const int r = quarter * 8 + rr;
      float2 v = nb0; nb0 = nb1; nb1 = nb2; nb2 = nb3;
      int rn = r + 4; rn = (rn < NR) ? rn : (NR - 1);   // clamped redundant tail load
      nb3 = gptr[(size_t)rn * GPP];

      float x = v.x, y = v.y;
      float f2x = x * x, f2y = y * y;
      cpx += f2x; cpy += f2y;
      float nv2 = fmaxf(x, v2x);
      v2x = (x > v1x) ? v1x : nv2; v1x = fmaxf(v1x, x);   // top-2, first-index
      nv2 = fmaxf(y, v2y);
      v2y = (y > v1y) ? v1y : nv2; v1y = fmaxf(v1y, y);
      ssum += x + y;
      float s0t = f2x + f2y;
      sii += s0t * rrq;

      float mv = fmaxf(x, y);
      mcpack |= ((y > x) ? 1u : 0u) << rr;     // strict >: x (lower idx) wins ties
      lds_s0[rr * 256 + t] = s0t;
      lds_mv[rr * 256 + t] = mv;
    }

    // ---- epilogue: transpose-reduce 8 r's in parallel (8 er x 32 eg) ----
    lds_mc[t] = mcpack; mcpack = 0u;
    __syncthreads();                           // arena writes visible
    const int er = t & 7;                      // which r this thread reduces
    const int eg = t >> 3;                     // which 8-row group
    float es0 = 0.f, esx = 0.f, esy = 0.f;
    float bmv = -INFINITY; int brow = 0;
#pragma unroll
    for (int k = 0; k < 8; ++k) {
      int row = eg * 8 + ((k + er) & 7);       // rotation: 2-way bank alias only (free)
      float s0v = lds_s0[er * 256 + row];
      float mvv = lds_mv[er * 256 + row];
      unsigned gq = (unsigned)(chunk * 256 + row);
      float fiq = (float)(gq / 1152u);         // i = (gq*2)/2304
      float fjq = (float)((gq / 24u) % 48u);   // j = (gq*2/48)%48
      es0 += s0v;
      esx = fmaf(s0v, fiq, esx);
      esy = fmaf(s0v, fjq, esy);
      if (mvv > bmv || (mvv == bmv && row < brow)) { bmv = mvv; brow = row; }
    }
    unsigned bidx = (unsigned)((chunk * 256 + brow) * 2) + ((lds_mc[brow] >> er) & 1u);

    // combine the 8 eg-partials per er within the wave (lane bits 3,4,5)
#pragma unroll
    for (int m = 8; m <= 32; m <<= 1) {
      es0 += __shfl_xor(es0, m);
      esx += __shfl_xor(esx, m);
      esy += __shfl_xor(esy, m);
      float omv = __shfl_xor(bmv, m);
      unsigned oix = (unsigned)__shfl_xor((int)bidx, m);
      if (omv > bmv || (omv == bmv && oix < bidx)) { bmv = omv; bidx = oix; }
    }
    if (lane < 8) {
      comb_s0[wave][lane] = es0; comb_sx[wave][lane] = esx; comb_sy[wave][lane] = esy;
      comb_mv[wave][lane] = bmv; comb_idx[wave][lane] = bidx;
    }
    __syncthreads();                           // comb visible + arena reads done
    if (t < 8) {
      float ps0 = 0.f, psx = 0.f, psy = 0.f, pmv = -INFINITY;
      unsigned pidx = 0xffffffffu;
#pragma unroll
      for (int w = 0; w < 4; ++w) {
        ps0 += comb_s0[w][t]; psx += comb_sx[w][t]; psy += comb_sy[w][t];
        if (comb_mv[w][t] > pmv || (comb_mv[w][t] == pmv && comb_idx[w][t] < pidx)) {
          pmv = comb_mv[w][t]; pidx = comb_idx[w][t];
        }
      }
      // chunk-major, 32-B entries: each block owns a private 1-KB region -> no false sharing
      PPartP o; o.s0 = ps0; o.sx = psx; o.sy = psy; o.mv = pmv; o.idx = pidx;
      o.pad[0] = 0; o.pad[1] = 0; o.pad[2] = 0;
      pp[(size_t)chunk * NPLANES + b * NR + quarter * 8 + t] = o;
    }
    __syncthreads();                           // arena reuse for next quarter
  }

  // ---- div epilogue (f2@argmax == v1^2) + global sums ----
  float A = 0.f, Bs = 0.f, C = 0.f;
  {
    float m1 = v1x, m1sq = m1 * m1, rest = cpx - m1sq;
    A += m1sq * rest + v2x * v2x * m1sq;
    Bs += m1 * rest + v2x * m1sq;
    C += cpx;
    m1 = v1y; m1sq = m1 * m1; rest = cpy - m1sq;
    A += m1sq * rest + v2y * v2y * m1sq;
    Bs += m1 * rest + v2y * m1sq;
    C += cpy;
  }
  double dA = A, dB = Bs, dC = C, dS = ssum, dI = sii;
#pragma unroll
  for (int off = 32; off; off >>= 1) {
    dA += __shfl_down(dA, off);
    dB += __shfl_down(dB, off);
    dC += __shfl_down(dC, off);
    dS += __shfl_down(dS, off);
    dI += __shfl_down(dI, off);
  }
  if (lane == 0) { ld[wave][0]=dA; ld[wave][1]=dB; ld[wave][2]=dC; ld[wave][3]=dS; ld[wave][4]=dI; }
  __syncthreads();
  if (t == 0) {
    double a=0, bb=0, cc=0, ss=0, si=0;
#pragma unroll
    for (int w = 0; w < 4; ++w) { a+=ld[w][0]; bb+=ld[w][1]; cc+=ld[w][2]; ss+=ld[w][3]; si+=ld[w][4]; }
    blk[(size_t)bid*8+0]=a; blk[(size_t)bid*8+1]=bb; blk[(size_t)bid*8+2]=cc;
    blk[(size_t)bid*8+3]=ss; blk[(size_t)bid*8+4]=si;           // 64-B stride
  }
}

// ------------- fused finalize: per-plane combine + last-block final scalars -------------
__global__ __launch_bounds__(256)
void k_reduce(const PPartP* __restrict__ pp, const double* __restrict__ blk,
              double* __restrict__ planeDis, double* __restrict__ divpart,
              unsigned* __restrict__ counter, float* __restrict__ out) {
  __shared__ double ls[4][3];
  __shared__ float lmv4[4];
  __shared__ unsigned lidx4[4];
  __shared__ double fin[4][6];
  __shared__ int lastFlag;

  const int p = blockIdx.x;               // plane = b*32 + r
  const int t = threadIdx.x;
  const int wave = t >> 6, lane = t & 63;

  // ---- part 1: combine 216 chunk-partials of plane p ----
  double s0 = 0, sx = 0, sy = 0;
  float mv = -INFINITY; unsigned idx = 0xffffffffu;
  if (t < CHUNKS) {
    PPartP v = pp[(size_t)t * NPLANES + p];
    s0 = v.s0; sx = v.sx; sy = v.sy; mv = v.mv; idx = v.idx;
  }
#pragma unroll
  for (int off = 32; off; off >>= 1) {
    s0 += __shfl_down(s0, off);
    sx += __shfl_down(sx, off);
    sy += __shfl_down(sy, off);
    float omv = __shfl_down(mv, off);
    unsigned oix = (unsigned)__shfl_down((int)idx, off);
    if (omv > mv || (omv == mv && oix < idx)) { mv = omv; idx = oix; }
  }
  if (lane == 0) { ls[wave][0] = s0; ls[wave][1] = sx; ls[wave][2] = sy; lmv4[wave] = mv; lidx4[wave] = idx; }
  __syncthreads();
  if (t == 0) {
    double a0 = 0, a1 = 0, a2 = 0; float bm = -INFINITY; unsigned bi = 0xffffffffu;
#pragma unroll
    for (int w = 0; w < 4; ++w) {
      a0 += ls[w][0]; a1 += ls[w][1]; a2 += ls[w][2];
      if (lmv4[w] > bm || (lmv4[w] == bm && lidx4[w] < bi)) { bm = lmv4[w]; bi = lidx4[w]; }
    }
    int am = (int)bi;
    int mx = am / HD;
    int rem = am - mx * HD;
    int my = rem / W48;
    int mz = rem - my * W48;
    double dmx = mx, dmy = my, dmz = mz;
    // sum_k (mz-k)^2, k=0..47 = 48 mz^2 - 2256 mz + 35720 ; times W*H=2304
    planeDis[p] = (dmx*dmx + dmy*dmy) * a0 - 2.0*dmx*a1 - 2.0*dmy*a2
                + 2304.0 * (48.0*dmz*dmz - 2256.0*dmz + 35720.0);
  }

  // ---- part 2: this block's slice of div/global sums (rows p, p+256, ...) ----
  double A = 0, Bs = 0, C = 0, S = 0, SI = 0;
  if (t < 7) {
    int i = p + 256 * t;
    if (i < MAIN_BLOCKS) {
      const double* bb = blk + (size_t)i * 8;
      A = bb[0]; Bs = bb[1]; C = bb[2]; S = bb[3]; SI = bb[4];
    }
  }
#pragma unroll
  for (int off = 4; off; off >>= 1) {
    A  += __shfl_down(A, off);
    Bs += __shfl_down(Bs, off);
    C  += __shfl_down(C, off);
    S  += __shfl_down(S, off);
    SI += __shfl_down(SI, off);
  }
  if (t == 0) {
    double* dp = divpart + (size_t)p * 5;
    dp[0] = A; dp[1] = Bs; dp[2] = C; dp[3] = S; dp[4] = SI;
  }
  __syncthreads();

  // ---- last-block final reduction ----
  if (t == 0) {
    __threadfence();                              // release planeDis/divpart
    unsigned old = atomicAdd(counter, 1u);        // device-scope
    lastFlag = (old == 255u);
  }
  __syncthreads();
  if (lastFlag) {
    __threadfence();                              // acquire other blocks' writes
    double dis = planeDis[t];                     // 256 threads = 256 planes
    const double* dp = divpart + (size_t)t * 5;
    double fA = dp[0], fB = dp[1], fC = dp[2], fS = dp[3], fI = dp[4];
#pragma unroll
    for (int off = 32; off; off >>= 1) {
      dis += __shfl_down(dis, off);
      fA  += __shfl_down(fA, off);
      fB  += __shfl_down(fB, off);
      fC  += __shfl_down(fC, off);
      fS  += __shfl_down(fS, off);
      fI  += __shfl_down(fI, off);
    }
    if (lane == 0) {
      fin[wave][0] = dis; fin[wave][1] = fA; fin[wave][2] = fB;
      fin[wave][3] = fC;  fin[wave][4] = fS; fin[wave][5] = fI;
    }
    __syncthreads();
    if (t == 0) {
      double td = 0, tA = 0, tB = 0, tC = 0, tS = 0, tI = 0;
#pragma unroll
      for (int w = 0; w < 4; ++w) {
        td += fin[w][0]; tA += fin[w][1]; tB += fin[w][2];
        tC += fin[w][3]; tS += fin[w][4]; tI += fin[w][5];
      }
      double mgr = tS / NTOT;
      out[0] = (float)((td + tI) / NTOT);
      out[1] = (float)((tA - 2.0*mgr*tB + mgr*mgr*tC) / NTOT);
    }
  }
}

extern "C" void kernel_launch(void* const* d_in, const int* in_sizes, int n_in,
                              void* d_out, int out_size, void* d_ws, size_t ws_size,
                              hipStream_t stream) {
  // inputs: [0]=backbone_feature (unused), [1]=grouping_result (unused), [2]=feature
  const float* feat = (const float*)d_in[2];
  float* out = (float*)d_out;

  PPartP* pp       = (PPartP*)((char*)d_ws + PP_OFF);
  double* blk      = (double*)((char*)d_ws + BLK_OFF);
  double* planeDis = (double*)((char*)d_ws + PD_OFF);
  double* divpart  = (double*)((char*)d_ws + DP_OFF);
  unsigned* cnt    = (unsigned*)((char*)d_ws + CNT_OFF);

  hipMemsetAsync(cnt, 0, 4, stream);              // reset last-block counter each launch
  k_main<<<MAIN_BLOCKS, TPB, 0, stream>>>(feat, pp, blk);
  k_reduce<<<NPLANES, 256, 0, stream>>>(pp, blk, planeDis, divpart, cnt, out);
}

// Round 9
// 59.716 us; speedup vs baseline: 3.7994x; 1.0493x over previous
//
#include <hip/hip_runtime.h>
#include <math.h>

#define W48 48
#define HD 2304
#define WHD 110592
#define NR 32
#define NB 8
#define QPP 27648            // float4 groups per (b,r) plane
#define TPB 256
#define CHUNKS 108           // QPP / 256
#define MAIN_BLOCKS 864      // NB * CHUNKS
#define NPLANES 256
#define NTOT 28311552.0

struct PPartP { float s0, sx, sy, mv; unsigned idx; unsigned pad[3]; }; // 32 B padded

// ws layout (bytes)
#define PP_OFF   0u
#define BLK_OFF  884736u               // 108*256*32
#define PD_OFF   940032u               // + 864*8*8
#define DP_OFF   942080u               // + 256*8
#define CNT_OFF  952320u               // + 256*5*8

// ---- fused single-pass kernel (R5-proven structure): float4/thread, 16-r LDS halves ----
__global__ __launch_bounds__(256, 4)   // cap VGPR at 128 -> 4 waves/SIMD
void k_main(const float* __restrict__ feat, PPartP* __restrict__ pp,
            double* __restrict__ blk) {
  __shared__ float    lds_s0[16 * 256];    // 16 KB  [r16][t]
  __shared__ float    lds_mv[16 * 256];    // 16 KB  [r16][t]
  __shared__ unsigned lds_mc[256];         // 1 KB   packed mc, 2b per r16
  __shared__ float comb_s0[256], comb_sx[256], comb_sy[256];   // [eg][er]
  __shared__ float comb_mv[256];
  __shared__ unsigned comb_idx[256];
  __shared__ double ld[4][5];

  const int bid = blockIdx.x;
  const int t = threadIdx.x;
  const int b = bid / CHUNKS;
  const int chunk = bid - b * CHUNKS;
  const int qbase = chunk * 256 + t;
  const float4* gptr = reinterpret_cast<const float4*>(feat) + (size_t)b * (NR * QPP) + qbase;

  const int p0 = qbase * 4;
  const float fi = (float)(p0 / HD);
  const float fj = (float)((p0 / W48) % W48);   // constant over the 4 elems (4 | 48)
  const float rrq = fi * fi + fj * fj;

  float v1[4], v2[4], cp[4];
#pragma unroll
  for (int c = 0; c < 4; ++c) { v1[c] = -INFINITY; v2[c] = -INFINITY; cp[c] = 0.f; }
  float ssum = 0.f, sii = 0.f;
  unsigned mcpack = 0u;

  float4 nb0 = gptr[0];
  float4 nb1 = gptr[(size_t)QPP];
  float4 nb2 = gptr[2 * (size_t)QPP];

  const int wave = t >> 6, lane = t & 63;

  for (int half = 0; half < 2; ++half) {
#pragma unroll 4
    for (int rr = 0; rr < 16; ++rr) {
      const int r = half * 16 + rr;
      float4 v = nb0; nb0 = nb1; nb1 = nb2;
      if (r < NR - 3) nb2 = gptr[(size_t)(r + 3) * QPP];

      float vv[4] = {v.x, v.y, v.z, v.w};
      float f2[4];
#pragma unroll
      for (int c = 0; c < 4; ++c) {
        float f = vv[c];
        f2[c] = f * f;
        cp[c] += f2[c];
        ssum += f;
        float nv2 = fmaxf(f, v2[c]);
        v2[c] = (f > v1[c]) ? v1[c] : nv2;     // top-2 insert, first-index semantics
        v1[c] = fmaxf(v1[c], f);
      }
      float s0t = (f2[0] + f2[1]) + (f2[2] + f2[3]);
      sii += s0t * rrq;

      float mv = fmaxf(fmaxf(vv[0], vv[1]), fmaxf(vv[2], vv[3]));
      int mc = (mv == vv[0]) ? 0 : ((mv == vv[1]) ? 1 : ((mv == vv[2]) ? 2 : 3)); // first idx
      mcpack |= (unsigned)mc << (2 * rr);
      lds_s0[rr * 256 + t] = s0t;
      lds_mv[rr * 256 + t] = mv;
    }

    // ---- epilogue: transpose-reduce the 16 r's in parallel (16 er x 16 eg) ----
    lds_mc[t] = mcpack; mcpack = 0u;
    __syncthreads();                       // arena writes visible
    const int er = t & 15;                 // which r this thread reduces
    const int eg = t >> 4;                 // which 16-row group
    float es0 = 0.f, esx = 0.f, esy = 0.f;
    float bmv = -INFINITY; int brow = 0;
#pragma unroll
    for (int k = 0; k < 16; ++k) {
      int row = eg * 16 + ((k + er) & 15);     // rotation: 2-way bank alias only (free)
      float s0v = lds_s0[er * 256 + row];
      float mvv = lds_mv[er * 256 + row];
      unsigned q = (unsigned)(chunk * 256 + row);
      float fiq = (float)(q / 576u);           // i = (q*4)/2304
      float fjq = (float)((q / 12u) % 48u);    // j = (q*4/48)%48
      es0 += s0v;
      esx = fmaf(s0v, fiq, esx);
      esy = fmaf(s0v, fjq, esy);
      if (mvv > bmv || (mvv == bmv && row < brow)) { bmv = mvv; brow = row; }
    }
    unsigned bidx = (unsigned)((chunk * 256 + brow) * 4) + ((lds_mc[brow] >> (2 * er)) & 3u);
    __syncthreads();                       // arena reads done (safe to reuse)
    comb_s0[t] = es0; comb_sx[t] = esx; comb_sy[t] = esy;
    comb_mv[t] = bmv; comb_idx[t] = bidx;
    __syncthreads();                       // comb visible
    if (t < 16) {
      float ps0 = 0.f, psx = 0.f, psy = 0.f, pmv = -INFINITY;
      unsigned pidx = 0xffffffffu;
#pragma unroll
      for (int g2 = 0; g2 < 16; ++g2) {
        int ii = g2 * 16 + t;
        ps0 += comb_s0[ii]; psx += comb_sx[ii]; psy += comb_sy[ii];
        if (comb_mv[ii] > pmv || (comb_mv[ii] == pmv && comb_idx[ii] < pidx)) {
          pmv = comb_mv[ii]; pidx = comb_idx[ii];
        }
      }
      // chunk-major, 32-B entries: each block owns a private 1-KB line-aligned region
      PPartP o; o.s0 = ps0; o.sx = psx; o.sy = psy; o.mv = pmv; o.idx = pidx;
      o.pad[0] = 0; o.pad[1] = 0; o.pad[2] = 0;
      pp[(size_t)chunk * NPLANES + b * NR + half * 16 + t] = o;
    }
    __syncthreads();                       // arena reuse for next half
  }

  // ---- div epilogue (f2@argmax == v1^2) + global sums ----
  float A = 0.f, Bs = 0.f, C = 0.f;
#pragma unroll
  for (int c = 0; c < 4; ++c) {
    float m1 = v1[c], m1sq = m1 * m1;
    float rest = cp[c] - m1sq;
    A  += m1sq * rest + v2[c] * v2[c] * m1sq;
    Bs += m1 * rest + v2[c] * m1sq;
    C  += cp[c];
  }
  double dA = A, dB = Bs, dC = C, dS = ssum, dI = sii;
#pragma unroll
  for (int off = 32; off; off >>= 1) {
    dA += __shfl_down(dA, off);
    dB += __shfl_down(dB, off);
    dC += __shfl_down(dC, off);
    dS += __shfl_down(dS, off);
    dI += __shfl_down(dI, off);
  }
  if (lane == 0) { ld[wave][0]=dA; ld[wave][1]=dB; ld[wave][2]=dC; ld[wave][3]=dS; ld[wave][4]=dI; }
  __syncthreads();
  if (t == 0) {
    double a=0, bb=0, cc=0, ss=0, si=0;
#pragma unroll
    for (int w = 0; w < 4; ++w) { a+=ld[w][0]; bb+=ld[w][1]; cc+=ld[w][2]; ss+=ld[w][3]; si+=ld[w][4]; }
    blk[(size_t)bid*8+0]=a; blk[(size_t)bid*8+1]=bb; blk[(size_t)bid*8+2]=cc;
    blk[(size_t)bid*8+3]=ss; blk[(size_t)bid*8+4]=si;           // 64-B stride, private line
  }
}

// ------------- fused finalize: per-plane combine + last-block final scalars -------------
__global__ __launch_bounds__(256)
void k_reduce(const PPartP* __restrict__ pp, const double* __restrict__ blk,
              double* __restrict__ planeDis, double* __restrict__ divpart,
              unsigned* __restrict__ counter, float* __restrict__ out) {
  __shared__ double ls[4][3];
  __shared__ float lmv4[4];
  __shared__ unsigned lidx4[4];
  __shared__ double fin[4][6];
  __shared__ int lastFlag;

  const int p = blockIdx.x;               // plane = b*32 + r
  const int t = threadIdx.x;
  const int wave = t >> 6, lane = t & 63;

  // ---- part 1: combine 108 chunk-partials of plane p ----
  double s0 = 0, sx = 0, sy = 0;
  float mv = -INFINITY; unsigned idx = 0xffffffffu;
  if (t < CHUNKS) {
    PPartP v = pp[(size_t)t * NPLANES + p];
    s0 = v.s0; sx = v.sx; sy = v.sy; mv = v.mv; idx = v.idx;
  }
#pragma unroll
  for (int off = 32; off; off >>= 1) {
    s0 += __shfl_down(s0, off);
    sx += __shfl_down(sx, off);
    sy += __shfl_down(sy, off);
    float omv = __shfl_down(mv, off);
    unsigned oix = (unsigned)__shfl_down((int)idx, off);
    if (omv > mv || (omv == mv && oix < idx)) { mv = omv; idx = oix; }
  }
  if (lane == 0) { ls[wave][0] = s0; ls[wave][1] = sx; ls[wave][2] = sy; lmv4[wave] = mv; lidx4[wave] = idx; }
  __syncthreads();
  if (t == 0) {
    double a0 = 0, a1 = 0, a2 = 0; float bm = -INFINITY; unsigned bi = 0xffffffffu;
#pragma unroll
    for (int w = 0; w < 4; ++w) {
      a0 += ls[w][0]; a1 += ls[w][1]; a2 += ls[w][2];
      if (lmv4[w] > bm || (lmv4[w] == bm && lidx4[w] < bi)) { bm = lmv4[w]; bi = lidx4[w]; }
    }
    int am = (int)bi;
    int mx = am / HD;
    int rem = am - mx * HD;
    int my = rem / W48;
    int mz = rem - my * W48;
    double dmx = mx, dmy = my, dmz = mz;
    // sum_k (mz-k)^2, k=0..47 = 48 mz^2 - 2256 mz + 35720 ; times W*H=2304
    planeDis[p] = (dmx*dmx + dmy*dmy) * a0 - 2.0*dmx*a1 - 2.0*dmy*a2
                + 2304.0 * (48.0*dmz*dmz - 2256.0*dmz + 35720.0);
  }

  // ---- part 2: this block's slice of div/global sums (rows p, p+256, p+512, p+768) ----
  double A = 0, Bs = 0, C = 0, S = 0, SI = 0;
  if (t < 4) {
    int i = p + 256 * t;
    if (i < MAIN_BLOCKS) {
      const double* bb = blk + (size_t)i * 8;
      A = bb[0]; Bs = bb[1]; C = bb[2]; S = bb[3]; SI = bb[4];
    }
  }
#pragma unroll
  for (int off = 2; off; off >>= 1) {
    A  += __shfl_down(A, off);
    Bs += __shfl_down(Bs, off);
    C  += __shfl_down(C, off);
    S  += __shfl_down(S, off);
    SI += __shfl_down(SI, off);
  }
  if (t == 0) {
    double* dp = divpart + (size_t)p * 5;
    dp[0] = A; dp[1] = Bs; dp[2] = C; dp[3] = S; dp[4] = SI;
  }
  __syncthreads();

  // ---- last-block final reduction ----
  if (t == 0) {
    __threadfence();                              // release planeDis/divpart
    unsigned old = atomicAdd(counter, 1u);        // device-scope
    lastFlag = (old == 255u);
  }
  __syncthreads();
  if (lastFlag) {
    __threadfence();                              // acquire other blocks' writes
    double dis = planeDis[t];                     // 256 threads = 256 planes
    const double* dp = divpart + (size_t)t * 5;
    double fA = dp[0], fB = dp[1], fC = dp[2], fS = dp[3], fI = dp[4];
#pragma unroll
    for (int off = 32; off; off >>= 1) {
      dis += __shfl_down(dis, off);
      fA  += __shfl_down(fA, off);
      fB  += __shfl_down(fB, off);
      fC  += __shfl_down(fC, off);
      fS  += __shfl_down(fS, off);
      fI  += __shfl_down(fI, off);
    }
    if (lane == 0) {
      fin[wave][0] = dis; fin[wave][1] = fA; fin[wave][2] = fB;
      fin[wave][3] = fC;  fin[wave][4] = fS; fin[wave][5] = fI;
    }
    __syncthreads();
    if (t == 0) {
      double td = 0, tA = 0, tB = 0, tC = 0, tS = 0, tI = 0;
#pragma unroll
      for (int w = 0; w < 4; ++w) {
        td += fin[w][0]; tA += fin[w][1]; tB += fin[w][2];
        tC += fin[w][3]; tS += fin[w][4]; tI += fin[w][5];
      }
      double mgr = tS / NTOT;
      out[0] = (float)((td + tI) / NTOT);
      out[1] = (float)((tA - 2.0*mgr*tB + mgr*mgr*tC) / NTOT);
    }
  }
}

extern "C" void kernel_launch(void* const* d_in, const int* in_sizes, int n_in,
                              void* d_out, int out_size, void* d_ws, size_t ws_size,
                              hipStream_t stream) {
  // inputs: [0]=backbone_feature (unused), [1]=grouping_result (unused), [2]=feature
  const float* feat = (const float*)d_in[2];
  float* out = (float*)d_out;

  PPartP* pp       = (PPartP*)((char*)d_ws + PP_OFF);
  double* blk      = (double*)((char*)d_ws + BLK_OFF);
  double* planeDis = (double*)((char*)d_ws + PD_OFF);
  double* divpart  = (double*)((char*)d_ws + DP_OFF);
  unsigned* cnt    = (unsigned*)((char*)d_ws + CNT_OFF);

  hipMemsetAsync(cnt, 0, 4, stream);              // reset last-block counter each launch
  k_main<<<MAIN_BLOCKS, TPB, 0, stream>>>(feat, pp, blk);
  k_reduce<<<NPLANES, 256, 0, stream>>>(pp, blk, planeDis, divpart, cnt, out);
}

// Round 10
// 54.517 us; speedup vs baseline: 4.1617x; 1.0954x over previous
//
#include <hip/hip_runtime.h>
#include <math.h>

#define W48 48
#define HD 2304
#define WHD 110592
#define NR 32
#define NB 8
#define QPP 27648            // float4 groups per (b,r) plane
#define TPB 256
#define CHUNKS 108           // QPP / 256
#define MAIN_BLOCKS 864      // NB * CHUNKS
#define NPLANES 256
#define NTOT 28311552.0

struct PPartP { float s0, sx, sy, mv; unsigned idx; unsigned pad[3]; }; // 32 B padded

// ws layout (bytes)
#define PP_OFF   0u
#define BLK_OFF  884736u               // 108*256*32
#define PD_OFF   940032u               // + 864*8*8
#define DP_OFF   942080u               // + 256*8
#define CNT_OFF  952320u               // + 256*5*8

// ---- fused single-pass kernel: float4/thread, 16-r LDS halves ----
// NOTE (toolchain law, measured R6-R9): __launch_bounds__(256,N) caps VGPR at 256/N.
// N=2 -> cap 128: fits the ~75-100 natural footprint with NO scratch spill,
// while 128 VGPR still permits 4 waves/SIMD (occupancy equals the LDS limit).
__global__ __launch_bounds__(256, 2)
void k_main(const float* __restrict__ feat, PPartP* __restrict__ pp,
            double* __restrict__ blk) {
  __shared__ float    lds_s0[16 * 256];    // 16 KB  [r16][t]
  __shared__ float    lds_mv[16 * 256];    // 16 KB  [r16][t]
  __shared__ unsigned lds_mc[256];         // 1 KB   packed mc, 2b per r16
  __shared__ float comb_s0[256], comb_sx[256], comb_sy[256];   // [eg][er]
  __shared__ float comb_mv[256];
  __shared__ unsigned comb_idx[256];
  __shared__ double ld[4][5];

  const int bid = blockIdx.x;
  const int t = threadIdx.x;
  const int b = bid / CHUNKS;
  const int chunk = bid - b * CHUNKS;
  const int qbase = chunk * 256 + t;
  const float4* gptr = reinterpret_cast<const float4*>(feat) + (size_t)b * (NR * QPP) + qbase;

  const int p0 = qbase * 4;
  const float fi = (float)(p0 / HD);
  const float fj = (float)((p0 / W48) % W48);   // constant over the 4 elems (4 | 48)
  const float rrq = fi * fi + fj * fj;

  float v1[4], v2[4], cp[4];
#pragma unroll
  for (int c = 0; c < 4; ++c) { v1[c] = -INFINITY; v2[c] = -INFINITY; cp[c] = 0.f; }
  float ssum = 0.f, sii = 0.f;
  unsigned mcpack = 0u;

  float4 nb0 = gptr[0];
  float4 nb1 = gptr[(size_t)QPP];
  float4 nb2 = gptr[2 * (size_t)QPP];

  const int wave = t >> 6, lane = t & 63;

  for (int half = 0; half < 2; ++half) {
#pragma unroll 4
    for (int rr = 0; rr < 16; ++rr) {
      const int r = half * 16 + rr;
      float4 v = nb0; nb0 = nb1; nb1 = nb2;
      if (r < NR - 3) nb2 = gptr[(size_t)(r + 3) * QPP];

      float vv[4] = {v.x, v.y, v.z, v.w};
      float f2[4];
#pragma unroll
      for (int c = 0; c < 4; ++c) {
        float f = vv[c];
        f2[c] = f * f;
        cp[c] += f2[c];
        ssum += f;
        float nv2 = fmaxf(f, v2[c]);
        v2[c] = (f > v1[c]) ? v1[c] : nv2;     // top-2 insert, first-index semantics
        v1[c] = fmaxf(v1[c], f);
      }
      float s0t = (f2[0] + f2[1]) + (f2[2] + f2[3]);
      sii += s0t * rrq;

      float mv = fmaxf(fmaxf(vv[0], vv[1]), fmaxf(vv[2], vv[3]));
      int mc = (mv == vv[0]) ? 0 : ((mv == vv[1]) ? 1 : ((mv == vv[2]) ? 2 : 3)); // first idx
      mcpack |= (unsigned)mc << (2 * rr);
      lds_s0[rr * 256 + t] = s0t;
      lds_mv[rr * 256 + t] = mv;
    }

    // ---- epilogue: transpose-reduce the 16 r's in parallel (16 er x 16 eg) ----
    lds_mc[t] = mcpack; mcpack = 0u;
    __syncthreads();                       // arena writes visible
    const int er = t & 15;                 // which r this thread reduces
    const int eg = t >> 4;                 // which 16-row group
    float es0 = 0.f, esx = 0.f, esy = 0.f;
    float bmv = -INFINITY; int brow = 0;
#pragma unroll
    for (int k = 0; k < 16; ++k) {
      int row = eg * 16 + ((k + er) & 15);     // rotation: 2-way bank alias only (free)
      float s0v = lds_s0[er * 256 + row];
      float mvv = lds_mv[er * 256 + row];
      unsigned q = (unsigned)(chunk * 256 + row);
      float fiq = (float)(q / 576u);           // i = (q*4)/2304
      float fjq = (float)((q / 12u) % 48u);    // j = (q*4/48)%48
      es0 += s0v;
      esx = fmaf(s0v, fiq, esx);
      esy = fmaf(s0v, fjq, esy);
      if (mvv > bmv || (mvv == bmv && row < brow)) { bmv = mvv; brow = row; }
    }
    unsigned bidx = (unsigned)((chunk * 256 + brow) * 4) + ((lds_mc[brow] >> (2 * er)) & 3u);
    __syncthreads();                       // arena reads done (safe to reuse)
    comb_s0[t] = es0; comb_sx[t] = esx; comb_sy[t] = esy;
    comb_mv[t] = bmv; comb_idx[t] = bidx;
    __syncthreads();                       // comb visible
    if (t < 16) {
      float ps0 = 0.f, psx = 0.f, psy = 0.f, pmv = -INFINITY;
      unsigned pidx = 0xffffffffu;
#pragma unroll
      for (int g2 = 0; g2 < 16; ++g2) {
        int ii = g2 * 16 + t;
        ps0 += comb_s0[ii]; psx += comb_sx[ii]; psy += comb_sy[ii];
        if (comb_mv[ii] > pmv || (comb_mv[ii] == pmv && comb_idx[ii] < pidx)) {
          pmv = comb_mv[ii]; pidx = comb_idx[ii];
        }
      }
      // chunk-major, 32-B entries: each block owns a private 1-KB line-aligned region
      PPartP o; o.s0 = ps0; o.sx = psx; o.sy = psy; o.mv = pmv; o.idx = pidx;
      o.pad[0] = 0; o.pad[1] = 0; o.pad[2] = 0;
      pp[(size_t)chunk * NPLANES + b * NR + half * 16 + t] = o;
    }
    __syncthreads();                       // arena reuse for next half
  }

  // ---- div epilogue (f2@argmax == v1^2) + global sums ----
  float A = 0.f, Bs = 0.f, C = 0.f;
#pragma unroll
  for (int c = 0; c < 4; ++c) {
    float m1 = v1[c], m1sq = m1 * m1;
    float rest = cp[c] - m1sq;
    A  += m1sq * rest + v2[c] * v2[c] * m1sq;
    Bs += m1 * rest + v2[c] * m1sq;
    C  += cp[c];
  }
  double dA = A, dB = Bs, dC = C, dS = ssum, dI = sii;
#pragma unroll
  for (int off = 32; off; off >>= 1) {
    dA += __shfl_down(dA, off);
    dB += __shfl_down(dB, off);
    dC += __shfl_down(dC, off);
    dS += __shfl_down(dS, off);
    dI += __shfl_down(dI, off);
  }
  if (lane == 0) { ld[wave][0]=dA; ld[wave][1]=dB; ld[wave][2]=dC; ld[wave][3]=dS; ld[wave][4]=dI; }
  __syncthreads();
  if (t == 0) {
    double a=0, bb=0, cc=0, ss=0, si=0;
#pragma unroll
    for (int w = 0; w < 4; ++w) { a+=ld[w][0]; bb+=ld[w][1]; cc+=ld[w][2]; ss+=ld[w][3]; si+=ld[w][4]; }
    blk[(size_t)bid*8+0]=a; blk[(size_t)bid*8+1]=bb; blk[(size_t)bid*8+2]=cc;
    blk[(size_t)bid*8+3]=ss; blk[(size_t)bid*8+4]=si;           // 64-B stride, private line
  }
}

// ------------- fused finalize: per-plane combine + last-block final scalars -------------
__global__ __launch_bounds__(256)
void k_reduce(const PPartP* __restrict__ pp, const double* __restrict__ blk,
              double* __restrict__ planeDis, double* __restrict__ divpart,
              unsigned* __restrict__ counter, float* __restrict__ out) {
  __shared__ double ls[4][3];
  __shared__ float lmv4[4];
  __shared__ unsigned lidx4[4];
  __shared__ double fin[4][6];
  __shared__ int lastFlag;

  const int p = blockIdx.x;               // plane = b*32 + r
  const int t = threadIdx.x;
  const int wave = t >> 6, lane = t & 63;

  // ---- part 1: combine 108 chunk-partials of plane p ----
  double s0 = 0, sx = 0, sy = 0;
  float mv = -INFINITY; unsigned idx = 0xffffffffu;
  if (t < CHUNKS) {
    PPartP v = pp[(size_t)t * NPLANES + p];
    s0 = v.s0; sx = v.sx; sy = v.sy; mv = v.mv; idx = v.idx;
  }
#pragma unroll
  for (int off = 32; off; off >>= 1) {
    s0 += __shfl_down(s0, off);
    sx += __shfl_down(sx, off);
    sy += __shfl_down(sy, off);
    float omv = __shfl_down(mv, off);
    unsigned oix = (unsigned)__shfl_down((int)idx, off);
    if (omv > mv || (omv == mv && oix < idx)) { mv = omv; idx = oix; }
  }
  if (lane == 0) { ls[wave][0] = s0; ls[wave][1] = sx; ls[wave][2] = sy; lmv4[wave] = mv; lidx4[wave] = idx; }
  __syncthreads();
  if (t == 0) {
    double a0 = 0, a1 = 0, a2 = 0; float bm = -INFINITY; unsigned bi = 0xffffffffu;
#pragma unroll
    for (int w = 0; w < 4; ++w) {
      a0 += ls[w][0]; a1 += ls[w][1]; a2 += ls[w][2];
      if (lmv4[w] > bm || (lmv4[w] == bm && lidx4[w] < bi)) { bm = lmv4[w]; bi = lidx4[w]; }
    }
    int am = (int)bi;
    int mx = am / HD;
    int rem = am - mx * HD;
    int my = rem / W48;
    int mz = rem - my * W48;
    double dmx = mx, dmy = my, dmz = mz;
    // sum_k (mz-k)^2, k=0..47 = 48 mz^2 - 2256 mz + 35720 ; times W*H=2304
    planeDis[p] = (dmx*dmx + dmy*dmy) * a0 - 2.0*dmx*a1 - 2.0*dmy*a2
                + 2304.0 * (48.0*dmz*dmz - 2256.0*dmz + 35720.0);
  }

  // ---- part 2: this block's slice of div/global sums (rows p, p+256, p+512, p+768) ----
  double A = 0, Bs = 0, C = 0, S = 0, SI = 0;
  if (t < 4) {
    int i = p + 256 * t;
    if (i < MAIN_BLOCKS) {
      const double* bb = blk + (size_t)i * 8;
      A = bb[0]; Bs = bb[1]; C = bb[2]; S = bb[3]; SI = bb[4];
    }
  }
#pragma unroll
  for (int off = 2; off; off >>= 1) {
    A  += __shfl_down(A, off);
    Bs += __shfl_down(Bs, off);
    C  += __shfl_down(C, off);
    S  += __shfl_down(S, off);
    SI += __shfl_down(SI, off);
  }
  if (t == 0) {
    double* dp = divpart + (size_t)p * 5;
    dp[0] = A; dp[1] = Bs; dp[2] = C; dp[3] = S; dp[4] = SI;
  }
  __syncthreads();

  // ---- last-block final reduction ----
  if (t == 0) {
    __threadfence();                              // release planeDis/divpart
    unsigned old = atomicAdd(counter, 1u);        // device-scope
    lastFlag = (old == 255u);
  }
  __syncthreads();
  if (lastFlag) {
    __threadfence();                              // acquire other blocks' writes
    double dis = planeDis[t];                     // 256 threads = 256 planes
    const double* dp = divpart + (size_t)t * 5;
    double fA = dp[0], fB = dp[1], fC = dp[2], fS = dp[3], fI = dp[4];
#pragma unroll
    for (int off = 32; off; off >>= 1) {
      dis += __shfl_down(dis, off);
      fA  += __shfl_down(fA, off);
      fB  += __shfl_down(fB, off);
      fC  += __shfl_down(fC, off);
      fS  += __shfl_down(fS, off);
      fI  += __shfl_down(fI, off);
    }
    if (lane == 0) {
      fin[wave][0] = dis; fin[wave][1] = fA; fin[wave][2] = fB;
      fin[wave][3] = fC;  fin[wave][4] = fS; fin[wave][5] = fI;
    }
    __syncthreads();
    if (t == 0) {
      double td = 0, tA = 0, tB = 0, tC = 0, tS = 0, tI = 0;
#pragma unroll
      for (int w = 0; w < 4; ++w) {
        td += fin[w][0]; tA += fin[w][1]; tB += fin[w][2];
        tC += fin[w][3]; tS += fin[w][4]; tI += fin[w][5];
      }
      double mgr = tS / NTOT;
      out[0] = (float)((td + tI) / NTOT);
      out[1] = (float)((tA - 2.0*mgr*tB + mgr*mgr*tC) / NTOT);
    }
  }
}

extern "C" void kernel_launch(void* const* d_in, const int* in_sizes, int n_in,
                              void* d_out, int out_size, void* d_ws, size_t ws_size,
                              hipStream_t stream) {
  // inputs: [0]=backbone_feature (unused), [1]=grouping_result (unused), [2]=feature
  const float* feat = (const float*)d_in[2];
  float* out = (float*)d_out;

  PPartP* pp       = (PPartP*)((char*)d_ws + PP_OFF);
  double* blk      = (double*)((char*)d_ws + BLK_OFF);
  double* planeDis = (double*)((char*)d_ws + PD_OFF);
  double* divpart  = (double*)((char*)d_ws + DP_OFF);
  unsigned* cnt    = (unsigned*)((char*)d_ws + CNT_OFF);

  hipMemsetAsync(cnt, 0, 4, stream);              // reset last-block counter each launch
  k_main<<<MAIN_BLOCKS, TPB, 0, stream>>>(feat, pp, blk);
  k_reduce<<<NPLANES, 256, 0, stream>>>(pp, blk, planeDis, divpart, cnt, out);
}

// Round 11
// 41.970 us; speedup vs baseline: 5.4059x; 1.2990x over previous
//
#include <hip/hip_runtime.h>
#include <math.h>

#define W48 48
#define HD 2304
#define WHD 110592
#define NR 32
#define NB 8
#define QPP 27648            // float4 groups per (b,r) plane
#define CHUNKS 108           // QPP / 256
#define MAIN_BLOCKS 864      // NB * CHUNKS
#define NTOT 28311552.0

struct PPart { float s0, sx, sy; unsigned key; unsigned idx; }; // 20 B

// ---------------- fused single-pass kernel, LDS-deferred per-r reductions ----------------
// Toolchain law (measured R6-R10): __launch_bounds__(256,N) caps VGPR at 256/N.
// N=2 -> 128-VGPR cap: no spill (R9 showed N=4's 64-cap spills ~35MB), and occupancy
// is LDS-limited to 4 blocks/CU either way -> strictly better than N=4.
__global__ __launch_bounds__(256, 2)
void k_main(const float* __restrict__ feat, PPart* __restrict__ pp,
            double* __restrict__ blk) {
  __shared__ float    lds_s0[16 * 256];    // 16 KB  [r16][t]
  __shared__ unsigned lds_key[16 * 256];   // 16 KB  [r16][t]
  __shared__ unsigned lds_mc[256];         // 1 KB   packed mc, 2b per r16
  __shared__ float comb_s0[256], comb_sx[256], comb_sy[256];   // [eg][er]
  __shared__ unsigned comb_key[256], comb_idx[256];
  __shared__ double ld[4][5];

  const int bid = blockIdx.x;
  const int t = threadIdx.x;
  const int b = bid / CHUNKS;
  const int chunk = bid - b * CHUNKS;
  const int qbase = chunk * 256 + t;
  const float4* gptr = reinterpret_cast<const float4*>(feat) + (size_t)b * (NR * QPP) + qbase;

  const int p0 = qbase * 4;
  const float fi = (float)(p0 / HD);
  const float fj = (float)((p0 / W48) % W48);   // constant over the 4 elems (4 | 48)
  const float rrq = fi * fi + fj * fj;

  float v1[4], v2[4], cp[4];
#pragma unroll
  for (int c = 0; c < 4; ++c) { v1[c] = -INFINITY; v2[c] = -INFINITY; cp[c] = 0.f; }
  float ssum = 0.f, sii = 0.f;
  unsigned mcpack = 0u;

  float4 nb0 = gptr[0];
  float4 nb1 = gptr[QPP];
  float4 nb2 = gptr[2 * (size_t)QPP];

  for (int half = 0; half < 2; ++half) {
#pragma unroll 4
    for (int rr = 0; rr < 16; ++rr) {
      const int r = half * 16 + rr;
      float4 v = nb0; nb0 = nb1; nb1 = nb2;
      if (r < NR - 3) nb2 = gptr[(size_t)(r + 3) * QPP];

      float vv[4] = {v.x, v.y, v.z, v.w};
      float f2[4];
#pragma unroll
      for (int c = 0; c < 4; ++c) {
        float f = vv[c];
        f2[c] = f * f;
        cp[c] += f2[c];
        ssum += f;
        float nv2 = fmaxf(f, v2[c]);
        v2[c] = (f > v1[c]) ? v1[c] : nv2;     // top-2 insert, first-index semantics
        v1[c] = fmaxf(v1[c], f);
      }
      float s0t = (f2[0] + f2[1]) + (f2[2] + f2[3]);
      sii += s0t * rrq;

      float mv = vv[0]; int mc = 0;
#pragma unroll
      for (int c = 1; c < 4; ++c) { if (vv[c] > mv) { mv = vv[c]; mc = c; } }  // strict >
      unsigned u = __float_as_uint(mv);
      unsigned key = u ^ ((unsigned)((int)u >> 31) | 0x80000000u);  // order-preserving

      mcpack |= (unsigned)mc << (2 * rr);
      lds_s0[rr * 256 + t] = s0t;
      lds_key[rr * 256 + t] = key;
    }

    // ---- epilogue for this half: transpose-reduce 16 r's in parallel ----
    lds_mc[t] = mcpack; mcpack = 0u;
    __syncthreads();                      // S1: main-arena writes visible
    const int er = t & 15;                // which r this thread reduces
    const int eg = t >> 4;                // row-group (16 rows each)
    float es0 = 0.f, esx = 0.f, esy = 0.f;
    unsigned bk = 0u; int brow = 0;       // real keys are always > 0
#pragma unroll
    for (int k = 0; k < 16; ++k) {
      int row = eg * 16 + ((k + er) & 15);   // rotation: bank-decorrelated
      float s0v   = lds_s0[er * 256 + row];
      unsigned kv = lds_key[er * 256 + row];
      unsigned q = (unsigned)(chunk * 256 + row);
      float fiq = (float)(q / 576u);
      float fjq = (float)((q / 12u) % 48u);
      es0 += s0v;
      esx = fmaf(s0v, fiq, esx);
      esy = fmaf(s0v, fjq, esy);
      if (kv > bk || (kv == bk && row < brow)) { bk = kv; brow = row; }
    }
    unsigned wmc = (lds_mc[brow] >> (2 * er)) & 3u;
    unsigned bidx = (unsigned)((chunk * 256 + brow) * 4) + wmc;
    __syncthreads();                      // S2: main-arena reads done (safe to reuse)
    comb_s0[t] = es0; comb_sx[t] = esx; comb_sy[t] = esy;
    comb_key[t] = bk; comb_idx[t] = bidx;
    __syncthreads();                      // S3: comb visible
    if (t < 16) {
      float ps0 = 0.f, psx = 0.f, psy = 0.f;
      unsigned fk = 0u, fidx = 0xffffffffu;
#pragma unroll
      for (int g2 = 0; g2 < 16; ++g2) {
        int ii = g2 * 16 + t;
        ps0 += comb_s0[ii]; psx += comb_sx[ii]; psy += comb_sy[ii];
        unsigned ck = comb_key[ii], ci = comb_idx[ii];
        if (ck > fk || (ck == fk && ci < fidx)) { fk = ck; fidx = ci; }
      }
      int plane = b * NR + half * 16 + t;
      PPart o; o.s0 = ps0; o.sx = psx; o.sy = psy; o.key = fk; o.idx = fidx;
      pp[(size_t)plane * CHUNKS + chunk] = o;
    }
    __syncthreads();                      // arena reuse for next half
  }

  // ---- div epilogue (f2@argmax == v1^2) + global sums ----
  float A = 0.f, Bs = 0.f, C = 0.f;
#pragma unroll
  for (int c = 0; c < 4; ++c) {
    float m1 = v1[c], m1sq = m1 * m1;
    float rest = cp[c] - m1sq;
    A  += m1sq * rest + v2[c] * v2[c] * m1sq;
    Bs += m1 * rest + v2[c] * m1sq;
    C  += cp[c];
  }
  double dA = A, dB = Bs, dC = C, dS = ssum, dI = sii;
  const int wave = t >> 6, lane = t & 63;
#pragma unroll
  for (int off = 32; off; off >>= 1) {
    dA += __shfl_down(dA, off);
    dB += __shfl_down(dB, off);
    dC += __shfl_down(dC, off);
    dS += __shfl_down(dS, off);
    dI += __shfl_down(dI, off);
  }
  if (lane == 0) { ld[wave][0]=dA; ld[wave][1]=dB; ld[wave][2]=dC; ld[wave][3]=dS; ld[wave][4]=dI; }
  __syncthreads();
  if (t == 0) {
    double a=0, bb=0, cc=0, ss=0, si=0;
#pragma unroll
    for (int w = 0; w < 4; ++w) { a+=ld[w][0]; bb+=ld[w][1]; cc+=ld[w][2]; ss+=ld[w][3]; si+=ld[w][4]; }
    blk[(size_t)bid*5+0]=a; blk[(size_t)bid*5+1]=bb; blk[(size_t)bid*5+2]=cc;
    blk[(size_t)bid*5+3]=ss; blk[(size_t)bid*5+4]=si;
  }
}

// ------------- stage 2: combine 108 chunk-partials per plane -------------
__global__ __launch_bounds__(128)
void k_planes(const PPart* __restrict__ pp, double* __restrict__ planeDis) {
  const int p = blockIdx.x;
  const int t = threadIdx.x;
  double s0 = 0, sx = 0, sy = 0;
  unsigned fkey = 0, idx = 0xffffffffu;
  if (t < CHUNKS) {
    PPart v = pp[(size_t)p * CHUNKS + t];
    s0 = v.s0; sx = v.sx; sy = v.sy; fkey = v.key; idx = v.idx;
  }
#pragma unroll
  for (int off = 32; off; off >>= 1) {
    s0 += __shfl_down(s0, off);
    sx += __shfl_down(sx, off);
    sy += __shfl_down(sy, off);
    unsigned ok = __shfl_down(fkey, off);
    unsigned oi = __shfl_down(idx, off);
    if (ok > fkey || (ok == fkey && oi < idx)) { fkey = ok; idx = oi; }
  }
  __shared__ double ls[2][3];
  __shared__ unsigned lk[2][2];
  const int wave = t >> 6, lane = t & 63;
  if (lane == 0) { ls[wave][0]=s0; ls[wave][1]=sx; ls[wave][2]=sy; lk[wave][0]=fkey; lk[wave][1]=idx; }
  __syncthreads();
  if (t == 0) {
    double a0=0, a1=0, a2=0; unsigned bk=0, bi=0xffffffffu;
#pragma unroll
    for (int w = 0; w < 2; ++w) {
      a0 += ls[w][0]; a1 += ls[w][1]; a2 += ls[w][2];
      if (lk[w][0] > bk || (lk[w][0]==bk && lk[w][1] < bi)) { bk = lk[w][0]; bi = lk[w][1]; }
    }
    int am = (int)bi;
    int mx = am / HD;
    int rem = am - mx * HD;
    int my = rem / W48;
    int mz = rem - my * W48;
    double dmx = mx, dmy = my, dmz = mz;
    // sum_k (mz-k)^2, k=0..47 = 48 mz^2 - 2256 mz + 35720 ; times W*H=2304
    planeDis[p] = (dmx*dmx + dmy*dmy) * a0 - 2.0*dmx*a1 - 2.0*dmy*a2
                + 2304.0 * (48.0*dmz*dmz - 2256.0*dmz + 35720.0);
  }
}

// ------------- stage 3: final scalars -------------
__global__ __launch_bounds__(256)
void k_fin(const double* __restrict__ planeDis, const double* __restrict__ blk,
           float* __restrict__ out) {
  const int t = threadIdx.x;
  double dis = planeDis[t];     // exactly 256 planes
  double A = 0, B = 0, C = 0, S = 0, SII = 0;
  for (int i = t; i < MAIN_BLOCKS; i += 256) {
    A   += blk[(size_t)i*5+0];
    B   += blk[(size_t)i*5+1];
    C   += blk[(size_t)i*5+2];
    S   += blk[(size_t)i*5+3];
    SII += blk[(size_t)i*5+4];
  }
#pragma unroll
  for (int off = 32; off; off >>= 1) {
    dis += __shfl_down(dis, off);
    A   += __shfl_down(A, off);
    B   += __shfl_down(B, off);
    C   += __shfl_down(C, off);
    S   += __shfl_down(S, off);
    SII += __shfl_down(SII, off);
  }
  __shared__ double ls[4][6];
  const int wave = t >> 6, lane = t & 63;
  if (lane == 0) {
    ls[wave][0]=dis; ls[wave][1]=A; ls[wave][2]=B; ls[wave][3]=C; ls[wave][4]=S; ls[wave][5]=SII;
  }
  __syncthreads();
  if (t == 0) {
    double td=0, tA=0, tB=0, tC=0, tS=0, tI=0;
#pragma unroll
    for (int w = 0; w < 4; ++w) {
      td+=ls[w][0]; tA+=ls[w][1]; tB+=ls[w][2]; tC+=ls[w][3]; tS+=ls[w][4]; tI+=ls[w][5];
    }
    double mgr = tS / NTOT;
    out[0] = (float)((td + tI) / NTOT);
    out[1] = (float)((tA - 2.0*mgr*tB + mgr*mgr*tC) / NTOT);
  }
}

extern "C" void kernel_launch(void* const* d_in, const int* in_sizes, int n_in,
                              void* d_out, int out_size, void* d_ws, size_t ws_size,
                              hipStream_t stream) {
  // inputs: [0]=backbone_feature (unused), [1]=grouping_result (unused), [2]=feature
  const float* feat = (const float*)d_in[2];
  float* out = (float*)d_out;

  PPart* pp = (PPart*)d_ws;                                   // 256*108*20 = 552960 B
  double* blk = (double*)((char*)d_ws + 552960);              // 864*5*8 = 34560 B
  double* planeDis = (double*)((char*)d_ws + 552960 + 34560); // 256*8 = 2048 B

  k_main<<<MAIN_BLOCKS, 256, 0, stream>>>(feat, pp, blk);
  k_planes<<<256, 128, 0, stream>>>(pp, planeDis);
  k_fin<<<1, 256, 0, stream>>>(planeDis, blk, out);
}

// Round 12
// 39.662 us; speedup vs baseline: 5.7204x; 1.0582x over previous
//
#include <hip/hip_runtime.h>
#include <math.h>

#define W48 48
#define HD 2304
#define WHD 110592
#define NR 32
#define NB 8
#define QPP 27648            // float4 groups per (b,r) plane
#define CHUNKS 108           // QPP / 256
#define MAIN_BLOCKS 864      // NB * CHUNKS
#define NTOT 28311552.0

struct PPart { float s0, sx, sy; unsigned key; unsigned idx; }; // 20 B

// ---------------- fused single-pass kernel, LDS-deferred per-r reductions ----------------
// Toolchain law (measured R6-R10): __launch_bounds__(256,N) caps VGPR at 256/N.
// N=2 -> 128-VGPR cap. R11 measured: VGPR=76, no spill, VALUBusy 20%, occ 21%
// -> latency-bound. This round: prefetch depth 3 -> 6 (+12 VGPR, ~2x MLP).
__global__ __launch_bounds__(256, 2)
void k_main(const float* __restrict__ feat, PPart* __restrict__ pp,
            double* __restrict__ blk) {
  __shared__ float    lds_s0[16 * 256];    // 16 KB  [r16][t]
  __shared__ unsigned lds_key[16 * 256];   // 16 KB  [r16][t]
  __shared__ unsigned lds_mc[256];         // 1 KB   packed mc, 2b per r16
  __shared__ float comb_s0[256], comb_sx[256], comb_sy[256];   // [eg][er]
  __shared__ unsigned comb_key[256], comb_idx[256];
  __shared__ double ld[4][5];

  const int bid = blockIdx.x;
  const int t = threadIdx.x;
  const int b = bid / CHUNKS;
  const int chunk = bid - b * CHUNKS;
  const int qbase = chunk * 256 + t;
  const float4* gptr = reinterpret_cast<const float4*>(feat) + (size_t)b * (NR * QPP) + qbase;

  const int p0 = qbase * 4;
  const float fi = (float)(p0 / HD);
  const float fj = (float)((p0 / W48) % W48);   // constant over the 4 elems (4 | 48)
  const float rrq = fi * fi + fj * fj;

  float v1[4], v2[4], cp[4];
#pragma unroll
  for (int c = 0; c < 4; ++c) { v1[c] = -INFINITY; v2[c] = -INFINITY; cp[c] = 0.f; }
  float ssum = 0.f, sii = 0.f;
  unsigned mcpack = 0u;

  // 6-deep rotating prefetch: ~6 KB in flight per wave
  float4 nb0 = gptr[0];
  float4 nb1 = gptr[(size_t)QPP];
  float4 nb2 = gptr[2 * (size_t)QPP];
  float4 nb3 = gptr[3 * (size_t)QPP];
  float4 nb4 = gptr[4 * (size_t)QPP];
  float4 nb5 = gptr[5 * (size_t)QPP];

  for (int half = 0; half < 2; ++half) {
#pragma unroll 4
    for (int rr = 0; rr < 16; ++rr) {
      const int r = half * 16 + rr;
      float4 v = nb0;
      nb0 = nb1; nb1 = nb2; nb2 = nb3; nb3 = nb4; nb4 = nb5;
      int rn = r + 6; rn = (rn < NR) ? rn : (NR - 1);   // clamped redundant tail load
      nb5 = gptr[(size_t)rn * QPP];

      float vv[4] = {v.x, v.y, v.z, v.w};
      float f2[4];
#pragma unroll
      for (int c = 0; c < 4; ++c) {
        float f = vv[c];
        f2[c] = f * f;
        cp[c] += f2[c];
        ssum += f;
        float nv2 = fmaxf(f, v2[c]);
        v2[c] = (f > v1[c]) ? v1[c] : nv2;     // top-2 insert, first-index semantics
        v1[c] = fmaxf(v1[c], f);
      }
      float s0t = (f2[0] + f2[1]) + (f2[2] + f2[3]);
      sii += s0t * rrq;

      float mv = vv[0]; int mc = 0;
#pragma unroll
      for (int c = 1; c < 4; ++c) { if (vv[c] > mv) { mv = vv[c]; mc = c; } }  // strict >
      unsigned u = __float_as_uint(mv);
      unsigned key = u ^ ((unsigned)((int)u >> 31) | 0x80000000u);  // order-preserving

      mcpack |= (unsigned)mc << (2 * rr);
      lds_s0[rr * 256 + t] = s0t;
      lds_key[rr * 256 + t] = key;
    }

    // ---- epilogue for this half: transpose-reduce 16 r's in parallel ----
    lds_mc[t] = mcpack; mcpack = 0u;
    __syncthreads();                      // S1: main-arena writes visible
    const int er = t & 15;                // which r this thread reduces
    const int eg = t >> 4;                // row-group (16 rows each)
    float es0 = 0.f, esx = 0.f, esy = 0.f;
    unsigned bk = 0u; int brow = 0;       // real keys are always > 0
#pragma unroll
    for (int k = 0; k < 16; ++k) {
      int row = eg * 16 + ((k + er) & 15);   // rotation: bank-decorrelated
      float s0v   = lds_s0[er * 256 + row];
      unsigned kv = lds_key[er * 256 + row];
      unsigned q = (unsigned)(chunk * 256 + row);
      float fiq = (float)(q / 576u);
      float fjq = (float)((q / 12u) % 48u);
      es0 += s0v;
      esx = fmaf(s0v, fiq, esx);
      esy = fmaf(s0v, fjq, esy);
      if (kv > bk || (kv == bk && row < brow)) { bk = kv; brow = row; }
    }
    unsigned wmc = (lds_mc[brow] >> (2 * er)) & 3u;
    unsigned bidx = (unsigned)((chunk * 256 + brow) * 4) + wmc;
    __syncthreads();                      // S2: main-arena reads done (safe to reuse)
    comb_s0[t] = es0; comb_sx[t] = esx; comb_sy[t] = esy;
    comb_key[t] = bk; comb_idx[t] = bidx;
    __syncthreads();                      // S3: comb visible
    if (t < 16) {
      float ps0 = 0.f, psx = 0.f, psy = 0.f;
      unsigned fk = 0u, fidx = 0xffffffffu;
#pragma unroll
      for (int g2 = 0; g2 < 16; ++g2) {
        int ii = g2 * 16 + t;
        ps0 += comb_s0[ii]; psx += comb_sx[ii]; psy += comb_sy[ii];
        unsigned ck = comb_key[ii], ci = comb_idx[ii];
        if (ck > fk || (ck == fk && ci < fidx)) { fk = ck; fidx = ci; }
      }
      int plane = b * NR + half * 16 + t;
      PPart o; o.s0 = ps0; o.sx = psx; o.sy = psy; o.key = fk; o.idx = fidx;
      pp[(size_t)plane * CHUNKS + chunk] = o;
    }
    __syncthreads();                      // arena reuse for next half
  }

  // ---- div epilogue (f2@argmax == v1^2) + global sums ----
  float A = 0.f, Bs = 0.f, C = 0.f;
#pragma unroll
  for (int c = 0; c < 4; ++c) {
    float m1 = v1[c], m1sq = m1 * m1;
    float rest = cp[c] - m1sq;
    A  += m1sq * rest + v2[c] * v2[c] * m1sq;
    Bs += m1 * rest + v2[c] * m1sq;
    C  += cp[c];
  }
  double dA = A, dB = Bs, dC = C, dS = ssum, dI = sii;
  const int wave = t >> 6, lane = t & 63;
#pragma unroll
  for (int off = 32; off; off >>= 1) {
    dA += __shfl_down(dA, off);
    dB += __shfl_down(dB, off);
    dC += __shfl_down(dC, off);
    dS += __shfl_down(dS, off);
    dI += __shfl_down(dI, off);
  }
  if (lane == 0) { ld[wave][0]=dA; ld[wave][1]=dB; ld[wave][2]=dC; ld[wave][3]=dS; ld[wave][4]=dI; }
  __syncthreads();
  if (t == 0) {
    double a=0, bb=0, cc=0, ss=0, si=0;
#pragma unroll
    for (int w = 0; w < 4; ++w) { a+=ld[w][0]; bb+=ld[w][1]; cc+=ld[w][2]; ss+=ld[w][3]; si+=ld[w][4]; }
    blk[(size_t)bid*5+0]=a; blk[(size_t)bid*5+1]=bb; blk[(size_t)bid*5+2]=cc;
    blk[(size_t)bid*5+3]=ss; blk[(size_t)bid*5+4]=si;
  }
}

// ------------- stage 2: combine 108 chunk-partials per plane -------------
__global__ __launch_bounds__(128)
void k_planes(const PPart* __restrict__ pp, double* __restrict__ planeDis) {
  const int p = blockIdx.x;
  const int t = threadIdx.x;
  double s0 = 0, sx = 0, sy = 0;
  unsigned fkey = 0, idx = 0xffffffffu;
  if (t < CHUNKS) {
    PPart v = pp[(size_t)p * CHUNKS + t];
    s0 = v.s0; sx = v.sx; sy = v.sy; fkey = v.key; idx = v.idx;
  }
#pragma unroll
  for (int off = 32; off; off >>= 1) {
    s0 += __shfl_down(s0, off);
    sx += __shfl_down(sx, off);
    sy += __shfl_down(sy, off);
    unsigned ok = __shfl_down(fkey, off);
    unsigned oi = __shfl_down(idx, off);
    if (ok > fkey || (ok == fkey && oi < idx)) { fkey = ok; idx = oi; }
  }
  __shared__ double ls[2][3];
  __shared__ unsigned lk[2][2];
  const int wave = t >> 6, lane = t & 63;
  if (lane == 0) { ls[wave][0]=s0; ls[wave][1]=sx; ls[wave][2]=sy; lk[wave][0]=fkey; lk[wave][1]=idx; }
  __syncthreads();
  if (t == 0) {
    double a0=0, a1=0, a2=0; unsigned bk=0, bi=0xffffffffu;
#pragma unroll
    for (int w = 0; w < 2; ++w) {
      a0 += ls[w][0]; a1 += ls[w][1]; a2 += ls[w][2];
      if (lk[w][0] > bk || (lk[w][0]==bk && lk[w][1] < bi)) { bk = lk[w][0]; bi = lk[w][1]; }
    }
    int am = (int)bi;
    int mx = am / HD;
    int rem = am - mx * HD;
    int my = rem / W48;
    int mz = rem - my * W48;
    double dmx = mx, dmy = my, dmz = mz;
    // sum_k (mz-k)^2, k=0..47 = 48 mz^2 - 2256 mz + 35720 ; times W*H=2304
    planeDis[p] = (dmx*dmx + dmy*dmy) * a0 - 2.0*dmx*a1 - 2.0*dmy*a2
                + 2304.0 * (48.0*dmz*dmz - 2256.0*dmz + 35720.0);
  }
}

// ------------- stage 3: final scalars -------------
__global__ __launch_bounds__(256)
void k_fin(const double* __restrict__ planeDis, const double* __restrict__ blk,
           float* __restrict__ out) {
  const int t = threadIdx.x;
  double dis = planeDis[t];     // exactly 256 planes
  double A = 0, B = 0, C = 0, S = 0, SII = 0;
  for (int i = t; i < MAIN_BLOCKS; i += 256) {
    A   += blk[(size_t)i*5+0];
    B   += blk[(size_t)i*5+1];
    C   += blk[(size_t)i*5+2];
    S   += blk[(size_t)i*5+3];
    SII += blk[(size_t)i*5+4];
  }
#pragma unroll
  for (int off = 32; off; off >>= 1) {
    dis += __shfl_down(dis, off);
    A   += __shfl_down(A, off);
    B   += __shfl_down(B, off);
    C   += __shfl_down(C, off);
    S   += __shfl_down(S, off);
    SII += __shfl_down(SII, off);
  }
  __shared__ double ls[4][6];
  const int wave = t >> 6, lane = t & 63;
  if (lane == 0) {
    ls[wave][0]=dis; ls[wave][1]=A; ls[wave][2]=B; ls[wave][3]=C; ls[wave][4]=S; ls[wave][5]=SII;
  }
  __syncthreads();
  if (t == 0) {
    double td=0, tA=0, tB=0, tC=0, tS=0, tI=0;
#pragma unroll
    for (int w = 0; w < 4; ++w) {
      td+=ls[w][0]; tA+=ls[w][1]; tB+=ls[w][2]; tC+=ls[w][3]; tS+=ls[w][4]; tI+=ls[w][5];
    }
    double mgr = tS / NTOT;
    out[0] = (float)((td + tI) / NTOT);
    out[1] = (float)((tA - 2.0*mgr*tB + mgr*mgr*tC) / NTOT);
  }
}

extern "C" void kernel_launch(void* const* d_in, const int* in_sizes, int n_in,
                              void* d_out, int out_size, void* d_ws, size_t ws_size,
                              hipStream_t stream) {
  // inputs: [0]=backbone_feature (unused), [1]=grouping_result (unused), [2]=feature
  const float* feat = (const float*)d_in[2];
  float* out = (float*)d_out;

  PPart* pp = (PPart*)d_ws;                                   // 256*108*20 = 552960 B
  double* blk = (double*)((char*)d_ws + 552960);              // 864*5*8 = 34560 B
  double* planeDis = (double*)((char*)d_ws + 552960 + 34560); // 256*8 = 2048 B

  k_main<<<MAIN_BLOCKS, 256, 0, stream>>>(feat, pp, blk);
  k_planes<<<256, 128, 0, stream>>>(pp, planeDis);
  k_fin<<<1, 256, 0, stream>>>(planeDis, blk, out);
}